// Round 8
// baseline (1670.139 us; speedup 1.0000x reference)
//
#include <hip/hip_runtime.h>
#include <hip/hip_bf16.h>

typedef __bf16 bf16x8 __attribute__((ext_vector_type(8)));
typedef __bf16 bf16x4 __attribute__((ext_vector_type(4)));
typedef float  f32x4  __attribute__((ext_vector_type(4)));

#define S_LEN  256
#define BATCH  16
#define EDIM   512
#define HDIM   512
#define VOCAB  32000
#define G4     2048          // 4*H
#define M_ROWS 4096          // S*B
#define NWG_LSTM 32
#define NTILE_N  (VOCAB / 128)   // 250 logit n-tiles
#define NTILE_M  (M_ROWS / 128)  // 32 logit m-tiles

// fused-launch block partition (order = dependency order; in-order dispatch)
#define NB_PROD 32
#define NB_XP   (16 * 32)            // 512 xp tiles (G4/128 x M_ROWS/128)
#define NB_LOG  (NTILE_M * NTILE_N)  // 8000 logit tiles
#define NB_LSM  M_ROWS               // 4096 logsm rows
#define B_XP0   NB_PROD
#define B_LOG0  (B_XP0 + NB_XP)
#define B_LSM0  (B_LOG0 + NB_LOG)
#define NB_ALL  (B_LSM0 + NB_LSM)    // 12640

// ------- ws layout (bytes) -------
#define OFF_CNT   0                         // int: LSTM step barrier counter
#define OFF_MIR   256                       // int: mirrored completed-step count
#define OFF_XPROW 512                       // int[32]: xp tiles done per row-block
#define OFF_CROW  1024                      // int[32]: logit tiles done per row-block
#define OFF_BIAS  4096                      // float[2048] = b_ih + b_hh
#define OFF_X     12288                     // bf16[4096*512] gathered embeddings
#define OFF_WIH   (OFF_X + 4194304)         // bf16[2048*512]
#define OFF_WLIN  (OFF_WIH + 2097152)       // bf16[32000*512]
#define OFF_XP    (OFF_WLIN + 32768000)     // float[4096*2048]
#define OFF_HS    (OFF_XP + 33554432)       // bf16[257*16*512]; slab 0 zeroed (h_0)
// total = 76,836,864 bytes

// ---- device-coherent (write-through to Infinity Cache) ops ----
__device__ __forceinline__ void store_short_sc(__bf16* p, __bf16 v) {
  unsigned short u = __builtin_bit_cast(unsigned short, v);
  asm volatile("global_store_short %0, %1, off sc0 sc1" :: "v"(p), "v"(u) : "memory");
}
__device__ __forceinline__ void store_f32_sc(float* p, float v) {
  asm volatile("global_store_dword %0, %1, off sc0 sc1" :: "v"(p), "v"(v) : "memory");
}
__device__ __forceinline__ void store_int_sc(int* p, int v) {
  asm volatile("global_store_dword %0, %1, off sc0 sc1" :: "v"(p), "v"(v) : "memory");
}
__device__ __forceinline__ int load_cnt_sc(const int* p) {
  int r;
  asm volatile("global_load_dword %0, %1, off sc0 sc1\n\ts_waitcnt vmcnt(0)"
               : "=v"(r) : "v"(p) : "memory");
  return r;
}

#define GLOAD_LDS(gsrc, ldst)                                                  \
  __builtin_amdgcn_global_load_lds(                                            \
      (const __attribute__((address_space(1))) void*)(gsrc),                   \
      (__attribute__((address_space(3))) void*)(ldst), 16, 0, 0)

// ---------------- merged prep kernel (block-range split, all independent) ----------------
__global__ __launch_bounds__(256) void k_prep(
    const int* __restrict__ tok, const float* __restrict__ embed, __bf16* __restrict__ xb,
    const float* __restrict__ W_ih, __bf16* __restrict__ wihb,
    const float* __restrict__ W_lin, __bf16* __restrict__ wlinb,
    const float* __restrict__ b_ih, const float* __restrict__ b_hh, float* __restrict__ bb) {
  const int b = blockIdx.x, tid = threadIdx.x;
  if (b < 2048) {                       // embedding gather+cast: 4096*128 float4 chunks
    int i = b * 256 + tid;
    int m = i >> 7, c = i & 127;
    int t = tok[m];
    float4 v = ((const float4*)(embed + (size_t)t * EDIM))[c];
    bf16x4 o = { (__bf16)v.x, (__bf16)v.y, (__bf16)v.z, (__bf16)v.w };
    ((bf16x4*)(xb + (size_t)m * EDIM))[c] = o;
  } else if (b < 3072) {                // W_ih cast: 262144 float4
    int i = (b - 2048) * 256 + tid;
    float4 v = ((const float4*)W_ih)[i];
    bf16x4 o = { (__bf16)v.x, (__bf16)v.y, (__bf16)v.z, (__bf16)v.w };
    ((bf16x4*)wihb)[i] = o;
  } else if (b < 5120) {                // W_lin cast: 4,096,000 float4, grid-stride
    for (int i = (b - 3072) * 256 + tid; i < VOCAB * HDIM / 4; i += 2048 * 256) {
      float4 v = ((const float4*)W_lin)[i];
      bf16x4 o = { (__bf16)v.x, (__bf16)v.y, (__bf16)v.z, (__bf16)v.w };
      ((bf16x4*)wlinb)[i] = o;
    }
  } else {                              // bias sum
    int i = (b - 5120) * 256 + tid;
    if (i < G4) bb[i] = b_ih[i] + b_hh[i];
  }
}

// ------- shared 128x128 MFMA GEMM tile body: D = A[M,K]*B[N,K]^T + bias -------
template <bool SC>
__device__ __forceinline__ void gemm_tile_body(
    const __bf16* __restrict__ A, const __bf16* __restrict__ B,
    float* __restrict__ D, const float* __restrict__ bias,
    int N, int K, int m0, int n0, __bf16* As, __bf16* Bs) {
  const int tid  = threadIdx.x;
  const int wave = tid >> 6, lane = tid & 63;
  const int wm   = (wave >> 1) * 64, wn = (wave & 1) * 64;
  const int lrow = lane & 15;
  const int kbyte = (lane >> 4) * 16;           // byte offset within 128B LDS row
  f32x4 acc[4][4];
  #pragma unroll
  for (int i = 0; i < 4; ++i)
    #pragma unroll
    for (int j = 0; j < 4; ++j) { acc[i][j][0]=0.f; acc[i][j][1]=0.f; acc[i][j][2]=0.f; acc[i][j][3]=0.f; }

  for (int k0 = 0; k0 < K; k0 += 64) {
    #pragma unroll
    for (int p = 0; p < 4; ++p) {
      int c = p * 256 + tid;                    // 16B chunk index, linear LDS fill
      int row = c >> 3, colE = (c & 7) * 8;     // row, bf16-element col
      GLOAD_LDS(A + (size_t)(m0 + row) * K + k0 + colE, (char*)As + c * 16);
      GLOAD_LDS(B + (size_t)(n0 + row) * K + k0 + colE, (char*)Bs + c * 16);
    }
    __syncthreads();                            // vmcnt(0) drain of load_lds
    #pragma unroll
    for (int ks = 0; ks < 2; ++ks) {
      bf16x8 af[4], bfv[4];
      #pragma unroll
      for (int i = 0; i < 4; ++i) {
        af[i]  = *(const bf16x8*)((const char*)As + (wm + i * 16 + lrow) * 128 + ks * 64 + kbyte);
        bfv[i] = *(const bf16x8*)((const char*)Bs + (wn + i * 16 + lrow) * 128 + ks * 64 + kbyte);
      }
      #pragma unroll
      for (int i = 0; i < 4; ++i)
        #pragma unroll
        for (int j = 0; j < 4; ++j)
          acc[i][j] = __builtin_amdgcn_mfma_f32_16x16x32_bf16(af[i], bfv[j], acc[i][j], 0, 0, 0);
    }
    __syncthreads();
  }
  const int col = lane & 15;
  const int rbase = (lane >> 4) * 4;
  #pragma unroll
  for (int i = 0; i < 4; ++i)
    #pragma unroll
    for (int j = 0; j < 4; ++j) {
      int nn = n0 + wn + j * 16 + col;
      float bv = bias[nn];
      #pragma unroll
      for (int rr = 0; rr < 4; ++rr) {
        int mm = m0 + wm + i * 16 + rbase + rr;
        float v = acc[i][j][rr] + bv;
        if constexpr (SC) store_f32_sc(&D[(size_t)mm * N + nn], v);
        else              D[(size_t)mm * N + nn] = v;
      }
    }
}

// ---------------- one fused launch: LSTM + xp GEMM + logits GEMM + log_softmax ----------------
// Blocks [0,32): persistent MFMA LSTM producers (R5 structure; poll xprow each
//   8 steps for the input projection produced in-launch).
// Blocks [32,544): xp-projection tiles -> sc1 stores + xprow[rb] counter.
// Blocks [544,8544): logit tiles; poll mir >= 8(mt+1); sc1 out stores + cnt_row[mt].
// Blocks [8544,12640): log_softmax rows; poll cnt_row[row>>7]==250; in-place.
// All cross-XCD handoffs: sc0sc1 write-through stores -> coherent L3; readers
// first-touch post-poll (and all buffer contents are deterministic across
// replays, so any stale clean L2 line equals the current value).
__global__ __launch_bounds__(256) void k_fused(
    const float* __restrict__ xp_ro, float* __restrict__ xp,
    const __bf16* __restrict__ xb, const __bf16* __restrict__ wihb,
    const float* __restrict__ bias_sum, const float* __restrict__ Whh,
    __bf16* __restrict__ hs_full, int* __restrict__ cnt, int* __restrict__ mir,
    int* __restrict__ xprow, int* __restrict__ cnt_row,
    const __bf16* __restrict__ wlinb, float* __restrict__ out,
    const float* __restrict__ b_lin) {
  __shared__ __align__(16) __bf16 As[128 * 64];
  __shared__ __align__(16) __bf16 Bs[128 * 64];
  const int tid = threadIdx.x;
  const int bid = blockIdx.x;

  if (bid >= B_LSM0) {
    // ---------------- log_softmax row (in-place on out) ----------------
    const int row = bid - B_LSM0;
    if (tid == 0) {
      while (load_cnt_sc(cnt_row + (row >> 7)) < NTILE_N) __builtin_amdgcn_s_sleep(32);
    }
    __syncthreads();
    float* p = out + (size_t)row * VOCAB;
    float m = -INFINITY, ssum = 0.f;
    for (int i = tid; i < VOCAB / 4; i += 256) {
      float4 v = ((const float4*)p)[i];
      float nm = fmaxf(fmaxf(m, v.x), fmaxf(fmaxf(v.y, v.z), v.w));
      if (nm > m) { ssum *= __expf(m - nm); m = nm; }
      ssum += __expf(v.x - m) + __expf(v.y - m) + __expf(v.z - m) + __expf(v.w - m);
    }
    #pragma unroll
    for (int off = 32; off > 0; off >>= 1) {
      float mo = __shfl_down(m, off);
      float so = __shfl_down(ssum, off);
      float nm = fmaxf(m, mo);
      ssum = ssum * __expf(m - nm) + so * __expf(mo - nm);
      m = nm;
    }
    __shared__ float sm[4], ss[4], lse_s;
    int wid = tid >> 6;
    if ((tid & 63) == 0) { sm[wid] = m; ss[wid] = ssum; }
    __syncthreads();
    if (tid == 0) {
      float M = sm[0], Ssum = ss[0];
      #pragma unroll
      for (int w = 1; w < 4; ++w) {
        float nm = fmaxf(M, sm[w]);
        Ssum = Ssum * __expf(M - nm) + ss[w] * __expf(sm[w] - nm);
        M = nm;
      }
      lse_s = M + logf(Ssum);
    }
    __syncthreads();
    const float lse = lse_s;
    for (int i = tid; i < VOCAB / 4; i += 256) {
      float4 v = ((const float4*)p)[i];
      v.x -= lse; v.y -= lse; v.z -= lse; v.w -= lse;
      ((float4*)p)[i] = v;
    }
    return;
  }

  if (bid >= B_LOG0) {
    // ---------------- logit tile: out[128,128] += hs * W_lin^T ----------------
    const int t  = bid - B_LOG0;
    const int mt = t / NTILE_N, nt = t % NTILE_N;
    if (tid == 0) {
      const int need = 8 * (mt + 1);           // steps 8*mt .. 8*mt+7 complete
      while (load_cnt_sc(mir) < need) __builtin_amdgcn_s_sleep(16);
    }
    __syncthreads();
    gemm_tile_body<true>(hs_full + BATCH * HDIM, wlinb, out, b_lin,
                         VOCAB, HDIM, mt * 128, nt * 128, As, Bs);
    __syncthreads();                           // drain sc1 out-stores (vmcnt 0)
    if (tid == 0)
      __hip_atomic_fetch_add(cnt_row + mt, 1, __ATOMIC_RELAXED, __HIP_MEMORY_SCOPE_AGENT);
    return;
  }

  if (bid >= B_XP0) {
    // ---------------- xp tile: xp[128,128] = xb * W_ih^T + bias ----------------
    const int t  = bid - B_XP0;
    const int rb = t >> 4, ntl = t & 15;       // row-block-major: earliest-needed first
    gemm_tile_body<true>(xb, wihb, xp, bias_sum, G4, EDIM, rb * 128, ntl * 128, As, Bs);
    __syncthreads();                           // drain sc1 xp-stores
    if (tid == 0)
      __hip_atomic_fetch_add(xprow + rb, 1, __ATOMIC_RELAXED, __HIP_MEMORY_SCOPE_AGENT);
    return;
  }

  // ---------------- producer: persistent LSTM (R5 structure) ----------------
  __builtin_amdgcn_s_setprio(1);
  const int lane = tid & 63;
  const int wv   = tid >> 6;               // 0..3
  const int W    = bid * 4 + wv;           // 0..127
  const int c0   = W * 4;                  // first cell owned by this wave
  const int nl   = lane & 15;              // MFMA col (n_local) / A row (batch)
  const int g    = nl >> 2, cl = nl & 3;
  const int Grow = g * 512 + c0 + cl;      // gate row in [0,2048)
  const int kb   = (lane >> 4) * 8;        // per-lane K offset
  const int B0   = (lane >> 4) * 4;        // batch base of acc regs

  // ---- B-frags: W_hh[Grow][k], fp32 -> bf16, 64 VGPRs, loaded once ----
  bf16x8 bfrag[16];
  #pragma unroll
  for (int kk = 0; kk < 16; ++kk) {
    const float4* src = (const float4*)(Whh + (size_t)Grow * 512 + kk * 32 + kb);
    float4 w0 = src[0], w1 = src[1];
    bf16x8 tt = { (__bf16)w0.x, (__bf16)w0.y, (__bf16)w0.z, (__bf16)w0.w,
                  (__bf16)w1.x, (__bf16)w1.y, (__bf16)w1.z, (__bf16)w1.w };
    bfrag[kk] = tt;
  }

  // wait for xp row-block 0 (16 tiles), then prime xq
  while (load_cnt_sc(xprow) < 16) __builtin_amdgcn_s_sleep(2);
  float c_reg[4] = {0.f, 0.f, 0.f, 0.f};
  f32x4 xq;                                // xp[s][B0+r][Grow], prefetched
  #pragma unroll
  for (int r = 0; r < 4; ++r) xq[r] = xp_ro[(size_t)(B0 + r) * G4 + Grow];

  for (int s = 0; s < S_LEN; ++s) {
    // A-frags: h_s[batch=nl][k], 16B loads (first-touch; L3-resident slab)
    const __bf16* hrow = hs_full + (size_t)s * 8192 + nl * 512 + kb;
    bf16x8 afrag[16];
    #pragma unroll
    for (int kk = 0; kk < 16; ++kk)
      afrag[kk] = *(const bf16x8*)(hrow + kk * 32);

    f32x4 acc0 = xq;                       // C-in = input projection (incl. biases)
    f32x4 acc1 = {0.f, 0.f, 0.f, 0.f};
    #pragma unroll
    for (int kk = 0; kk < 16; kk += 2) {
      acc0 = __builtin_amdgcn_mfma_f32_16x16x32_bf16(afrag[kk],     bfrag[kk],     acc0, 0, 0, 0);
      acc1 = __builtin_amdgcn_mfma_f32_16x16x32_bf16(afrag[kk + 1], bfrag[kk + 1], acc1, 0, 0, 0);
    }

    // prefetch next step's xp while MFMA drains (poll xp row-block each 8 steps)
    if (s + 1 < S_LEN) {
      if (((s + 1) & 7) == 0) {
        const int* xr = xprow + ((s + 1) >> 3);
        while (load_cnt_sc(xr) < 16) __builtin_amdgcn_s_sleep(2);
      }
      const float* nx = xp_ro + ((size_t)(s + 1) * BATCH + B0) * G4 + Grow;
      #pragma unroll
      for (int r = 0; r < 4; ++r) xq[r] = nx[(size_t)r * G4];
    }

    f32x4 gates;
    #pragma unroll
    for (int r = 0; r < 4; ++r) gates[r] = acc0[r] + acc1[r];

    // redistribute: this lane takes i,f,g,o of cell c0+(lane&3), batches B0..B0+3
    const int lbase = (lane & 48) | (lane & 3);
    __bf16* dstbase = hs_full + (size_t)(s + 1) * 8192 + (size_t)B0 * 512 + c0 + (lane & 3);
    #pragma unroll
    for (int r = 0; r < 4; ++r) {
      float ig = __shfl(gates[r], lbase + 0);
      float fg = __shfl(gates[r], lbase + 4);
      float gg = __shfl(gates[r], lbase + 8);
      float og = __shfl(gates[r], lbase + 12);
      float si = 1.f / (1.f + __expf(-ig));
      float sf = 1.f / (1.f + __expf(-fg));
      float so = 1.f / (1.f + __expf(-og));
      float ag = fabsf(gg), eg = __expf(-2.f * ag);
      float tg = __builtin_copysignf((1.f - eg) / (1.f + eg), gg);
      float c  = sf * c_reg[r] + si * tg;
      c_reg[r] = c;
      float ac = fabsf(c), ec = __expf(-2.f * ac);
      float tc = __builtin_copysignf((1.f - ec) / (1.f + ec), c);
      float h  = so * tc;
      if ((lane & 12) == 0)                // 16 writer lanes: store as soon as computed
        store_short_sc(dstbase + (size_t)r * 512, (__bf16)h);
    }

    __syncthreads();                       // every wave drains its sc1 stores (vmcnt 0)
    if (tid == 0) {
      __hip_atomic_fetch_add(cnt, 1, __ATOMIC_RELAXED, __HIP_MEMORY_SCOPE_AGENT);
      const int target = NWG_LSTM * (s + 1);
      while (load_cnt_sc(cnt) < target) {}
      if (bid == 0)                        // fire-and-forget mirror for consumers
        store_int_sc(mir, s + 1);
    }
    __syncthreads();
  }
}

extern "C" void kernel_launch(void* const* d_in, const int* in_sizes, int n_in,
                              void* d_out, int out_size, void* d_ws, size_t ws_size,
                              hipStream_t stream) {
  const int*   tok   = (const int*)d_in[0];
  // d_in[1] = input_lengths: unused by the reference
  const float* embed = (const float*)d_in[2];
  const float* W_ih  = (const float*)d_in[3];
  const float* W_hh  = (const float*)d_in[4];
  const float* b_ih  = (const float*)d_in[5];
  const float* b_hh  = (const float*)d_in[6];
  const float* W_lin = (const float*)d_in[7];
  const float* b_lin = (const float*)d_in[8];
  float* out = (float*)d_out;
  char*  ws  = (char*)d_ws;

  int*    cnt      = (int*)(ws + OFF_CNT);
  int*    mir      = (int*)(ws + OFF_MIR);
  int*    xprow    = (int*)(ws + OFF_XPROW);
  int*    cnt_row  = (int*)(ws + OFF_CROW);
  float*  bias_sum = (float*)(ws + OFF_BIAS);
  __bf16* xb       = (__bf16*)(ws + OFF_X);
  __bf16* wihb     = (__bf16*)(ws + OFF_WIH);
  __bf16* wlinb    = (__bf16*)(ws + OFF_WLIN);
  float*  xp       = (float*)(ws + OFF_XP);
  __bf16* hs_full  = (__bf16*)(ws + OFF_HS);

  // zero all counters + h_0 slab (required every replay; both small)
  hipMemsetAsync(ws + OFF_CNT, 0, 4096, stream);
  hipMemsetAsync(ws + OFF_HS, 0, BATCH * HDIM * sizeof(__bf16), stream);

  k_prep<<<5128, 256, 0, stream>>>(tok, embed, xb, W_ih, wihb, W_lin, wlinb,
                                   b_ih, b_hh, bias_sum);
  k_fused<<<NB_ALL, 256, 0, stream>>>(xp, xp, xb, wihb, bias_sum, W_hh, hs_full,
                                      cnt, mir, xprow, cnt_row, wlinb, out, b_lin);
}